// Round 15
// baseline (104.376 us; speedup 1.0000x reference)
//
#include <hip/hip_runtime.h>
#include <math.h>

// BigBird block-sparse attention.
// Path A: prep converts K,V -> bf16 fragment-linear in d_ws; main kernel =
//   1 wave per block, no LDS, no barriers. R15: DUAL-CHAIN — each wave splits
//   its tile list into two independent online-softmax chains (A,B) merged in
//   closed form at the end; 2x ILP inside the latency-bound wave.
// Path B (fallback if ws too small): R10 kernel (4-wave LDS double-buffered).
// B=2 H=16 M=N=4096 D=64 WM=WN=64 R=3 nb=64.
constexpr int B_  = 2;
constexpr int H_  = 16;
constexpr int M_  = 4096;
constexpr int NB_ = 64;
constexpr int R_  = 3;
constexpr float LOG2E  = 1.44269504089f;
constexpr float SCALE2 = 0.125f * LOG2E;          // (1/sqrt(64)) * log2(e)
constexpr float NEG2   = -10000.0f * LOG2E;

constexpr int PER_BH = 62 + 16;             // fallback: blocks per bh
constexpr int NWG    = B_ * H_ * PER_BH;    // 2496 = 8 * 312
constexpr int PACC_OFF = 0;                                  // [BH][2][8][64][64]
constexpr int PM_OFF   = B_ * H_ * 2 * 8 * 64 * 64;          // [BH][2][8][64]
constexpr int PL_OFF   = PM_OFF + B_ * H_ * 2 * 8 * 64;
constexpr size_t KV_BYTE_OFF = (size_t)(PL_OFF + B_ * H_ * 2 * 8 * 64) * 4;  // 8,650,752
constexpr size_t KV_BYTES    = (size_t)B_ * H_ * 64 * 1024 * 16;             // 33,554,432
constexpr size_t WS_NEED     = KV_BYTE_OFF + KV_BYTES;

// wave-level geometry: per bh: (62 mid + 16 edge-chunks) * 4 strips = 312 waves
constexpr int PER_BH1 = 312;
constexpr int NWG1    = B_ * H_ * PER_BH1;  // 9984 one-wave blocks = 8 * 1248

typedef short bf16x8 __attribute__((ext_vector_type(8)));   // 8 bf16 in 4 VGPRs
typedef float f32x4  __attribute__((ext_vector_type(4)));

__device__ __forceinline__ short bf16s(float x) {
    return __builtin_bit_cast(short, (__bf16)x);
}
__device__ __forceinline__ unsigned pack_bf16(float a, float b) {
    unsigned short ul = __builtin_bit_cast(unsigned short, (__bf16)a);
    unsigned short uh = __builtin_bit_cast(unsigned short, (__bf16)b);
    return (unsigned)ul | ((unsigned)uh << 16);
}

// key-block index for tile i (wave-uniform arithmetic, no arrays)
__device__ __forceinline__ int tile_kb(int e, int ch, int qb, int ra0, int ra1, int ra2, int i) {
    if (e >= 0) return ch * 8 + i;
    const int rnd = (i == 4) ? ra0 : ((i == 5) ? ra1 : ra2);
    if (qb == 1)        return (i < 3) ? i : ((i == 3) ? NB_ - 1 : rnd);
    if (qb == NB_ - 2)  return (i == 0) ? 0 : ((i < 4) ? 60 + i : rnd);
    if (i == 0) return 0;
    if (i < 4)  return qb - 2 + i;
    if (i < 7)  return rnd;
    return NB_ - 1;
}

// mask mode for tile i: 0=to_mask, 1=band, 2=rand
__device__ __forceinline__ int tile_mode(int e, int qb, int i, int& boff) {
    boff = 0;
    if (e >= 0) return 0;
    if (qb == 1 || qb == NB_ - 2) return (i >= 4) ? 2 : 0;
    if (i >= 1 && i < 4) { boff = (i - 1) * 64; return 1; }
    if (i >= 4 && i < 7) return 2;
    return 0;
}

// =====================================================================
// Prep: K,V fp32 -> bf16 fragment-linear tiles in ws.
// =====================================================================
__global__ __launch_bounds__(256)
void bigbird_prep(const float* __restrict__ k, const float* __restrict__ v,
                  int4* __restrict__ wskv)
{
    __shared__ float kt[64][66];
    __shared__ float vt[64][66];
    const int g = blockIdx.x;           // bh*64 + kb
    const int t = threadIdx.x;
    const int row = t >> 2, cc = (t & 3) * 16;
    const float* kp = k + (size_t)g * 4096 + row * 64 + cc;
    const float* vp = v + (size_t)g * 4096 + row * 64 + cc;
    #pragma unroll
    for (int j4 = 0; j4 < 4; ++j4) {
        *(float4*)&kt[row][cc + j4 * 4] = *(const float4*)(kp + j4 * 4);
        *(float4*)&vt[row][cc + j4 * 4] = *(const float4*)(vp + j4 * 4);
    }
    __syncthreads();
    #pragma unroll
    for (int cpt = 0; cpt < 4; ++cpt) {
        const int ch = t + cpt * 256;
        const int slot = ch >> 6, lane = ch & 63;
        bf16x8 o;
        if (slot < 8) {
            const int r  = 16 * (slot >> 1) + (lane & 15);
            const int c0 = 32 * (slot & 1) + 8 * (lane >> 4);
            #pragma unroll
            for (int j = 0; j < 8; ++j) o[j] = bf16s(kt[r][c0 + j]);
        } else {
            const int s2 = slot - 8;
            const int r0 = 32 * (s2 & 1) + 8 * (lane >> 4);
            const int c  = 16 * (s2 >> 1) + (lane & 15);
            #pragma unroll
            for (int j = 0; j < 8; ++j) o[j] = bf16s(vt[r0 + j][c]);
        }
        wskv[(size_t)g * 1024 + ch] = __builtin_bit_cast(int4, o);
    }
}

// =====================================================================
// Main (path A): 1 wave per block, dual independent softmax chains.
// =====================================================================
__global__ __launch_bounds__(64, 2)
void bigbird_1w(const float* __restrict__ q, const int4* __restrict__ wskv,
                const float* __restrict__ band_mask, const float* __restrict__ from_mask,
                const float* __restrict__ to_mask,   const float* __restrict__ from_blocked,
                const float* __restrict__ to_blocked, const int* __restrict__ rand_attn,
                float* __restrict__ out, float* __restrict__ ws)
{
    // bijective XCD swizzle: 9984 = 8 * 1248 (4 bh per XCD chunk)
    const int wg   = (blockIdx.x & 7) * (NWG1 / 8) + (blockIdx.x >> 3);
    const int bh   = wg / PER_BH1;
    const int idx  = wg % PER_BH1;
    const int item = idx >> 2;
    const int strip= idx & 3;
    const int h    = bh % H_;
    const int b    = bh / H_;
    int qb, e = -1, ch = 0;
    if (item < 62)      { qb = item + 1; }
    else if (item < 70) { e = 0; ch = item - 62; qb = 0; }
    else                { e = 1; ch = item - 70; qb = NB_ - 1; }

    const int l  = threadIdx.x;
    const int c  = l & 15;
    const int hh = l >> 4;

    int ra0 = 0, ra1 = 0, ra2 = 0;
    int nkb;
    if (e >= 0) nkb = 8;
    else {
        const int* ra = rand_attn + ((b * H_ + h) * (NB_ - 2) + (qb - 1)) * R_;
        ra0 = ra[0]; ra1 = ra[1]; ra2 = ra[2];
        nkb = (qb == 1 || qb == NB_ - 2) ? 7 : 8;
    }
    const int halfA = 4;                 // chain A: tiles 0..3; B: 4..nkb-1

    auto mask_ptr = [&](int kb, int mode, int boff) -> const float* {
        if (mode == 0) return to_mask + b * M_ + kb * 64 + 4 * hh;
        if (mode == 1) return band_mask + (((size_t)b * (NB_ - 4) + (qb - 2)) * 64 + (strip * 16 + c)) * 192 + boff + 4 * hh;
        return to_blocked + (b * NB_ + kb) * 64 + 4 * hh;
    };

    // Q B-fragments: lane holds Q[qb*64 + strip*16 + c][32dh + hh*8 + j]
    bf16x8 qf[2];
    {
        const float* qp = q + ((size_t)bh * M_ + (size_t)qb * 64 + strip * 16 + c) * 64 + hh * 8;
        #pragma unroll
        for (int dh = 0; dh < 2; ++dh) {
            float4 a0 = *(const float4*)(qp + dh * 32);
            float4 a1 = *(const float4*)(qp + dh * 32 + 4);
            bf16x8 qv;
            qv[0] = bf16s(a0.x); qv[1] = bf16s(a0.y); qv[2] = bf16s(a0.z); qv[3] = bf16s(a0.w);
            qv[4] = bf16s(a1.x); qv[5] = bf16s(a1.y); qv[6] = bf16s(a1.z); qv[7] = bf16s(a1.w);
            qf[dh] = qv;
        }
    }

    const float fbv = from_blocked[(b * NB_ + qb) * 64 + (strip * 16 + c)];

    float mA = -INFINITY, lA = 0.0f, mB = -INFINITY, lB = 0.0f;  // log2 domain
    f32x4 OA[4], OB[4];
    #pragma unroll
    for (int nf = 0; nf < 4; ++nf) {
        OA[nf][0]=0.f; OA[nf][1]=0.f; OA[nf][2]=0.f; OA[nf][3]=0.f;
        OB[nf][0]=0.f; OB[nf][1]=0.f; OB[nf][2]=0.f; OB[nf][3]=0.f;
    }

    for (int it = 0; it < halfA; ++it) {
        const int  iA   = it;
        const int  iB   = halfA + it;
        const bool hasB = (iB < nkb);

        // ---- metadata (scalar)
        const int kbA = tile_kb(e, ch, qb, ra0, ra1, ra2, iA);
        int boA; const int moA = tile_mode(e, qb, iA, boA);
        const int4* tbA = wskv + (size_t)(bh * 64 + kbA) * 1024;
        int kbB = 0, boB = 0, moB = 0; const int4* tbB = wskv;
        if (hasB) {
            kbB = tile_kb(e, ch, qb, ra0, ra1, ra2, iB);
            moB = tile_mode(e, qb, iB, boB);
            tbB = wskv + (size_t)(bh * 64 + kbB) * 1024;
        }

        // ---- K fragment loads, both chains (16 loads in flight)
        int4 kfrA[8], kfrB[8];
        #pragma unroll
        for (int s = 0; s < 8; ++s) kfrA[s] = tbA[s * 64 + l];
        if (hasB) {
            #pragma unroll
            for (int s = 0; s < 8; ++s) kfrB[s] = tbB[s * 64 + l];
        }
        // ---- mask loads, both chains
        float4 mpfA[4], mpfB[4];
        {
            const float* mp = mask_ptr(kbA, moA, boA);
            #pragma unroll
            for (int f = 0; f < 4; ++f) mpfA[f] = *(const float4*)(mp + 16 * f);
        }
        if (hasB) {
            const float* mp = mask_ptr(kbB, moB, boB);
            #pragma unroll
            for (int f = 0; f < 4; ++f) mpfB[f] = *(const float4*)(mp + 16 * f);
        }

        // ---- QK^T both chains (independent MFMA chains)
        f32x4 sfA[4], sfB[4];
        #pragma unroll
        for (int f = 0; f < 4; ++f) { sfA[f][0]=0.f; sfA[f][1]=0.f; sfA[f][2]=0.f; sfA[f][3]=0.f; }
        __builtin_amdgcn_s_setprio(1);
        #pragma unroll
        for (int f = 0; f < 4; ++f) {
            sfA[f] = __builtin_amdgcn_mfma_f32_16x16x32_bf16(
                         __builtin_bit_cast(bf16x8, kfrA[f * 2 + 0]), qf[0], sfA[f], 0, 0, 0);
            sfA[f] = __builtin_amdgcn_mfma_f32_16x16x32_bf16(
                         __builtin_bit_cast(bf16x8, kfrA[f * 2 + 1]), qf[1], sfA[f], 0, 0, 0);
        }
        __builtin_amdgcn_s_setprio(0);
        if (hasB) {
            #pragma unroll
            for (int f = 0; f < 4; ++f) { sfB[f][0]=0.f; sfB[f][1]=0.f; sfB[f][2]=0.f; sfB[f][3]=0.f; }
            __builtin_amdgcn_s_setprio(1);
            #pragma unroll
            for (int f = 0; f < 4; ++f) {
                sfB[f] = __builtin_amdgcn_mfma_f32_16x16x32_bf16(
                             __builtin_bit_cast(bf16x8, kfrB[f * 2 + 0]), qf[0], sfB[f], 0, 0, 0);
                sfB[f] = __builtin_amdgcn_mfma_f32_16x16x32_bf16(
                             __builtin_bit_cast(bf16x8, kfrB[f * 2 + 1]), qf[1], sfB[f], 0, 0, 0);
            }
            __builtin_amdgcn_s_setprio(0);
        }

        // ---- V fragment loads, both chains (K regs dead; in flight across
        //      both softmaxes)
        int4 vfrA[8], vfrB[8];
        #pragma unroll
        for (int s = 0; s < 8; ++s) vfrA[s] = tbA[(8 + s) * 64 + l];
        if (hasB) {
            #pragma unroll
            for (int s = 0; s < 8; ++s) vfrB[s] = tbB[(8 + s) * 64 + l];
        }

        // ================= chain A: softmax + PV =================
        {
            const float ms = (moA == 2) ? fbv : 1.0f;
            float p[4][4];
            float tmax = -INFINITY;
            #pragma unroll
            for (int f = 0; f < 4; ++f) {
                p[f][0] = sfA[f][0] * SCALE2 + (1.0f - ms * mpfA[f].x) * NEG2;
                p[f][1] = sfA[f][1] * SCALE2 + (1.0f - ms * mpfA[f].y) * NEG2;
                p[f][2] = sfA[f][2] * SCALE2 + (1.0f - ms * mpfA[f].z) * NEG2;
                p[f][3] = sfA[f][3] * SCALE2 + (1.0f - ms * mpfA[f].w) * NEG2;
                tmax = fmaxf(tmax, fmaxf(fmaxf(p[f][0], p[f][1]), fmaxf(p[f][2], p[f][3])));
            }
            tmax = fmaxf(tmax, __shfl_xor(tmax, 16));
            tmax = fmaxf(tmax, __shfl_xor(tmax, 32));
            const float mnew = fmaxf(mA, tmax);
            const float fs = exp2f(mA - mnew);
            float sum = 0.0f;
            #pragma unroll
            for (int f = 0; f < 4; ++f) {
                #pragma unroll
                for (int r = 0; r < 4; ++r) { p[f][r] = exp2f(p[f][r] - mnew); sum += p[f][r]; }
            }
            sum += __shfl_xor(sum, 16);
            sum += __shfl_xor(sum, 32);
            lA = lA * fs + sum;
            mA = mnew;

            const float fr0 = __shfl(fs, hh * 4 + 0);
            const float fr1 = __shfl(fs, hh * 4 + 1);
            const float fr2 = __shfl(fs, hh * 4 + 2);
            const float fr3 = __shfl(fs, hh * 4 + 3);
            #pragma unroll
            for (int nf = 0; nf < 4; ++nf) {
                OA[nf][0] *= fr0; OA[nf][1] *= fr1; OA[nf][2] *= fr2; OA[nf][3] *= fr3;
            }

            unsigned pks[4][2];
            #pragma unroll
            for (int f = 0; f < 4; ++f) {
                pks[f][0] = pack_bf16(p[f][0], p[f][1]);
                pks[f][1] = pack_bf16(p[f][2], p[f][3]);
            }
            #pragma unroll
            for (int kh = 0; kh < 2; ++kh) {
                unsigned ad[4];
                #pragma unroll
                for (int wq = 0; wq < 4; ++wq) {
                    const int pos = wq >> 1, ww = wq & 1;
                    const int src = c + 16 * ((2 * hh + pos) & 3);
                    const unsigned x = (unsigned)__shfl((int)pks[2 * kh][ww], src);
                    const unsigned y = (unsigned)__shfl((int)pks[2 * kh + 1][ww], src);
                    ad[wq] = (hh & 2) ? y : x;
                }
                const uint4 adv = make_uint4(ad[0], ad[1], ad[2], ad[3]);
                const bf16x8 pa = __builtin_bit_cast(bf16x8, adv);
                __builtin_amdgcn_s_setprio(1);
                #pragma unroll
                for (int nf = 0; nf < 4; ++nf) {
                    OA[nf] = __builtin_amdgcn_mfma_f32_16x16x32_bf16(
                                 pa, __builtin_bit_cast(bf16x8, vfrA[nf * 2 + kh]), OA[nf], 0, 0, 0);
                }
                __builtin_amdgcn_s_setprio(0);
            }
        }

        // ================= chain B: softmax + PV =================
        if (hasB) {
            const float ms = (moB == 2) ? fbv : 1.0f;
            float p[4][4];
            float tmax = -INFINITY;
            #pragma unroll
            for (int f = 0; f < 4; ++f) {
                p[f][0] = sfB[f][0] * SCALE2 + (1.0f - ms * mpfB[f].x) * NEG2;
                p[f][1] = sfB[f][1] * SCALE2 + (1.0f - ms * mpfB[f].y) * NEG2;
                p[f][2] = sfB[f][2] * SCALE2 + (1.0f - ms * mpfB[f].z) * NEG2;
                p[f][3] = sfB[f][3] * SCALE2 + (1.0f - ms * mpfB[f].w) * NEG2;
                tmax = fmaxf(tmax, fmaxf(fmaxf(p[f][0], p[f][1]), fmaxf(p[f][2], p[f][3])));
            }
            tmax = fmaxf(tmax, __shfl_xor(tmax, 16));
            tmax = fmaxf(tmax, __shfl_xor(tmax, 32));
            const float mnew = fmaxf(mB, tmax);
            const float fs = exp2f(mB - mnew);
            float sum = 0.0f;
            #pragma unroll
            for (int f = 0; f < 4; ++f) {
                #pragma unroll
                for (int r = 0; r < 4; ++r) { p[f][r] = exp2f(p[f][r] - mnew); sum += p[f][r]; }
            }
            sum += __shfl_xor(sum, 16);
            sum += __shfl_xor(sum, 32);
            lB = lB * fs + sum;
            mB = mnew;

            const float fr0 = __shfl(fs, hh * 4 + 0);
            const float fr1 = __shfl(fs, hh * 4 + 1);
            const float fr2 = __shfl(fs, hh * 4 + 2);
            const float fr3 = __shfl(fs, hh * 4 + 3);
            #pragma unroll
            for (int nf = 0; nf < 4; ++nf) {
                OB[nf][0] *= fr0; OB[nf][1] *= fr1; OB[nf][2] *= fr2; OB[nf][3] *= fr3;
            }

            unsigned pks[4][2];
            #pragma unroll
            for (int f = 0; f < 4; ++f) {
                pks[f][0] = pack_bf16(p[f][0], p[f][1]);
                pks[f][1] = pack_bf16(p[f][2], p[f][3]);
            }
            #pragma unroll
            for (int kh = 0; kh < 2; ++kh) {
                unsigned ad[4];
                #pragma unroll
                for (int wq = 0; wq < 4; ++wq) {
                    const int pos = wq >> 1, ww = wq & 1;
                    const int src = c + 16 * ((2 * hh + pos) & 3);
                    const unsigned x = (unsigned)__shfl((int)pks[2 * kh][ww], src);
                    const unsigned y = (unsigned)__shfl((int)pks[2 * kh + 1][ww], src);
                    ad[wq] = (hh & 2) ? y : x;
                }
                const uint4 adv = make_uint4(ad[0], ad[1], ad[2], ad[3]);
                const bf16x8 pa = __builtin_bit_cast(bf16x8, adv);
                __builtin_amdgcn_s_setprio(1);
                #pragma unroll
                for (int nf = 0; nf < 4; ++nf) {
                    OB[nf] = __builtin_amdgcn_mfma_f32_16x16x32_bf16(
                                 pa, __builtin_bit_cast(bf16x8, vfrB[nf * 2 + kh]), OB[nf], 0, 0, 0);
                }
                __builtin_amdgcn_s_setprio(0);
            }
        }
    }

    // ---- merge chains (closed form), then epilogue
    const float mM  = fmaxf(mA, mB);
    const float sAq = exp2f(mA - mM);
    const float sBq = exp2f(mB - mM);
    const float lM  = lA * sAq + lB * sBq;

    f32x4 O[4];
    #pragma unroll
    for (int r = 0; r < 4; ++r) {
        const float fAr = __shfl(sAq, hh * 4 + r);
        const float fBr = __shfl(sBq, hh * 4 + r);
        #pragma unroll
        for (int nf = 0; nf < 4; ++nf) O[nf][r] = OA[nf][r] * fAr + OB[nf][r] * fBr;
    }

    if (e < 0) {
        #pragma unroll
        for (int r = 0; r < 4; ++r) {
            const float lr  = __shfl(lM, hh * 4 + r);
            const int   qg  = qb * 64 + strip * 16 + hh * 4 + r;
            const float fmv = from_mask[b * M_ + qg];
            const float scl = fmv / lr;
            float* op = out + (((size_t)b * M_ + qg) * H_ + h) * 64 + c;
            #pragma unroll
            for (int nf = 0; nf < 4; ++nf) op[nf * 16] = O[nf][r] * scl;
        }
    } else {
        const int pe = (bh * 2 + e) * 8 + ch;
        #pragma unroll
        for (int r = 0; r < 4; ++r) {
            const int qlocal = strip * 16 + hh * 4 + r;
            float* pa = ws + PACC_OFF + ((size_t)pe * 64 + qlocal) * 64 + c;
            #pragma unroll
            for (int nf = 0; nf < 4; ++nf) pa[nf * 16] = O[nf][r];
        }
        if (hh == 0) {
            ws[PM_OFF + pe * 64 + strip * 16 + c] = mM;   // log2 domain
            ws[PL_OFF + pe * 64 + strip * 16 + c] = lM;
        }
    }
}

// =====================================================================
// Fallback (path B): R10 kernel, 4-wave LDS double-buffered.
// =====================================================================
__global__ __launch_bounds__(256, 4)
void bigbird_mfma(const float* __restrict__ q,  const float* __restrict__ k,
                  const float* __restrict__ v,  const float* __restrict__ band_mask,
                  const float* __restrict__ from_mask, const float* __restrict__ to_mask,
                  const float* __restrict__ from_blocked, const float* __restrict__ to_blocked,
                  const int*   __restrict__ rand_attn,   float* __restrict__ out,
                  float* __restrict__ ws)
{
    __shared__ int4 kf[2][8][64];
    __shared__ int4 vf[2][8][64];

    const int wg  = (blockIdx.x & 7) * (NWG / 8) + (blockIdx.x >> 3);
    const int bh  = wg / PER_BH;
    const int idx = wg % PER_BH;
    const int h   = bh % H_;
    const int b   = bh / H_;
    int qb, e = -1, ch = 0;
    if (idx < 62)      { qb = idx + 1; }
    else if (idx < 70) { e = 0; ch = idx - 62; qb = 0; }
    else               { e = 1; ch = idx - 70; qb = NB_ - 1; }

    const int t  = threadIdx.x;
    const int l  = t & 63;
    const int w  = t >> 6;
    const int c  = l & 15;
    const int hh = l >> 4;

    int ra0 = 0, ra1 = 0, ra2 = 0;
    int nkb;
    if (e >= 0) nkb = 8;
    else {
        const int* ra = rand_attn + ((b * H_ + h) * (NB_ - 2) + (qb - 1)) * R_;
        ra0 = ra[0]; ra1 = ra[1]; ra2 = ra[2];
        nkb = (qb == 1 || qb == NB_ - 2) ? 7 : 8;
    }

    const int rr  = t >> 2;
    const int cc4 = t & 3;
    const float* kbase = k + ((size_t)bh * M_ + rr) * 64 + cc4 * 16;
    const int kslot = (rr >> 4) * 2 + (cc4 >> 1);
    const int kr15  = rr & 15;
    const int kg0   = (cc4 & 1) * 2;

    const int d0v  = (t & 31) * 2;
    const int oct8 = t >> 5;
    const float* vbase = v + (size_t)bh * M_ * 64 + (size_t)(oct8 * 8) * 64 + d0v;
    const int vslot = (d0v >> 4) * 2 + (oct8 >> 2);
    const int vidx  = (oct8 & 3) * 16 + (d0v & 15);

    bf16x8 qf[2];
    {
        const float* qp = q + ((size_t)bh * M_ + (size_t)qb * 64 + w * 16 + c) * 64 + hh * 8;
        #pragma unroll
        for (int dh = 0; dh < 2; ++dh) {
            float4 a0 = *(const float4*)(qp + dh * 32);
            float4 a1 = *(const float4*)(qp + dh * 32 + 4);
            bf16x8 qv;
            qv[0] = bf16s(a0.x); qv[1] = bf16s(a0.y); qv[2] = bf16s(a0.z); qv[3] = bf16s(a0.w);
            qv[4] = bf16s(a1.x); qv[5] = bf16s(a1.y); qv[6] = bf16s(a1.z); qv[7] = bf16s(a1.w);
            qf[dh] = qv;
        }
    }

    const float fbv = from_blocked[(b * NB_ + qb) * 64 + (w * 16 + c)];

    float mrun = -INFINITY, lrun = 0.0f;
    f32x4 O[4];
    #pragma unroll
    for (int nf = 0; nf < 4; ++nf) { O[nf][0] = 0.f; O[nf][1] = 0.f; O[nf][2] = 0.f; O[nf][3] = 0.f; }

    float4 kr0, kr1, kr2, kr3;
    float2 vr[8];

    {
        const int kb0 = tile_kb(e, ch, qb, ra0, ra1, ra2, 0);
        const float4* kp4 = (const float4*)(kbase + (size_t)kb0 * 4096);
        kr0 = kp4[0]; kr1 = kp4[1]; kr2 = kp4[2]; kr3 = kp4[3];
        const float* vp = vbase + (size_t)kb0 * 4096;
        #pragma unroll
        for (int j = 0; j < 8; ++j) vr[j] = *(const float2*)(vp + j * 64);

        float kfl[16];
        kfl[0]=kr0.x; kfl[1]=kr0.y; kfl[2]=kr0.z; kfl[3]=kr0.w;
        kfl[4]=kr1.x; kfl[5]=kr1.y; kfl[6]=kr1.z; kfl[7]=kr1.w;
        kfl[8]=kr2.x; kfl[9]=kr2.y; kfl[10]=kr2.z; kfl[11]=kr2.w;
        kfl[12]=kr3.x; kfl[13]=kr3.y; kfl[14]=kr3.z; kfl[15]=kr3.w;
        bf16x8 o0, o1;
        #pragma unroll
        for (int j = 0; j < 8; ++j) { o0[j] = bf16s(kfl[j]); o1[j] = bf16s(kfl[8 + j]); }
        kf[0][kslot][kg0 * 16 + kr15]       = __builtin_bit_cast(int4, o0);
        kf[0][kslot][(kg0 + 1) * 16 + kr15] = __builtin_bit_cast(int4, o1);

        bf16x8 va, vb2;
        #pragma unroll
        for (int j = 0; j < 8; ++j) { va[j] = bf16s(vr[j].x); vb2[j] = bf16s(vr[j].y); }
        vf[0][vslot][vidx]     = __builtin_bit_cast(int4, va);
        vf[0][vslot][vidx + 1] = __builtin_bit_cast(int4, vb2);

        if (1 < nkb) {
            const int kb1 = tile_kb(e, ch, qb, ra0, ra1, ra2, 1);
            const float4* kn4 = (const float4*)(kbase + (size_t)kb1 * 4096);
            kr0 = kn4[0]; kr1 = kn4[1]; kr2 = kn4[2]; kr3 = kn4[3];
            const float* vn = vbase + (size_t)kb1 * 4096;
            #pragma unroll
            for (int j = 0; j < 8; ++j) vr[j] = *(const float2*)(vn + j * 64);
        }
    }
    __syncthreads();

    for (int it = 0; it < nkb; ++it) {
        const int cur = it & 1;
        const int kb = tile_kb(e, ch, qb, ra0, ra1, ra2, it);
        int boffC; const int modeC = tile_mode(e, qb, it, boffC);

        f32x4 sf[4];
        #pragma unroll
        for (int f = 0; f < 4; ++f) { sf[f][0]=0.f; sf[f][1]=0.f; sf[f][2]=0.f; sf[f][3]=0.f; }
        __builtin_amdgcn_s_setprio(1);
        #pragma unroll
        for (int f = 0; f < 4; ++f) {
            sf[f] = __builtin_amdgcn_mfma_f32_16x16x32_bf16(
                        __builtin_bit_cast(bf16x8, kf[cur][f * 2 + 0][l]), qf[0], sf[f], 0, 0, 0);
            sf[f] = __builtin_amdgcn_mfma_f32_16x16x32_bf16(
                        __builtin_bit_cast(bf16x8, kf[cur][f * 2 + 1][l]), qf[1], sf[f], 0, 0, 0);
        }
        __builtin_amdgcn_s_setprio(0);

        if (it + 1 < nkb) {
            const int nxt = cur ^ 1;
            float kfl[16];
            kfl[0]=kr0.x; kfl[1]=kr0.y; kfl[2]=kr0.z; kfl[3]=kr0.w;
            kfl[4]=kr1.x; kfl[5]=kr1.y; kfl[6]=kr1.z; kfl[7]=kr1.w;
            kfl[8]=kr2.x; kfl[9]=kr2.y; kfl[10]=kr2.z; kfl[11]=kr2.w;
            kfl[12]=kr3.x; kfl[13]=kr3.y; kfl[14]=kr3.z; kfl[15]=kr3.w;
            bf16x8 o0, o1;
            #pragma unroll
            for (int j = 0; j < 8; ++j) { o0[j] = bf16s(kfl[j]); o1[j] = bf16s(kfl[8 + j]); }
            kf[nxt][kslot][kg0 * 16 + kr15]       = __builtin_bit_cast(int4, o0);
            kf[nxt][kslot][(kg0 + 1) * 16 + kr15] = __builtin_bit_cast(int4, o1);

            bf16x8 va, vb2;
            #pragma unroll
            for (int j = 0; j < 8; ++j) { va[j] = bf16s(vr[j].x); vb2[j] = bf16s(vr[j].y); }
            vf[nxt][vslot][vidx]     = __builtin_bit_cast(int4, va);
            vf[nxt][vslot][vidx + 1] = __builtin_bit_cast(int4, vb2);
        }

        float msk[4][4];
        if (modeC == 0) {
            const float* mp = to_mask + b * M_ + kb * 64 + 4 * hh;
            #pragma unroll
            for (int f = 0; f < 4; ++f) {
                float4 mv = *(const float4*)(mp + 16 * f);
                msk[f][0] = mv.x; msk[f][1] = mv.y; msk[f][2] = mv.z; msk[f][3] = mv.w;
            }
        } else if (modeC == 1) {
            const float* mp = band_mask + (((size_t)b * (NB_ - 4) + (qb - 2)) * 64 + (w * 16 + c)) * 192 + boffC + 4 * hh;
            #pragma unroll
            for (int f = 0; f < 4; ++f) {
                float4 mv = *(const float4*)(mp + 16 * f);
                msk[f][0] = mv.x; msk[f][1] = mv.y; msk[f][2] = mv.z; msk[f][3] = mv.w;
            }
        } else {
            const float* mp = to_blocked + (b * NB_ + kb) * 64 + 4 * hh;
            #pragma unroll
            for (int f = 0; f < 4; ++f) {
                float4 mv = *(const float4*)(mp + 16 * f);
                msk[f][0] = fbv * mv.x; msk[f][1] = fbv * mv.y;
                msk[f][2] = fbv * mv.z; msk[f][3] = fbv * mv.w;
            }
        }

        if (it + 2 < nkb) {
            const int kb2 = tile_kb(e, ch, qb, ra0, ra1, ra2, it + 2);
            const float4* kp4 = (const float4*)(kbase + (size_t)kb2 * 4096);
            kr0 = kp4[0]; kr1 = kp4[1]; kr2 = kp4[2]; kr3 = kp4[3];
            const float* vp = vbase + (size_t)kb2 * 4096;
            #pragma unroll
            for (int j = 0; j < 8; ++j) vr[j] = *(const float2*)(vp + j * 64);
        }

        float p[4][4];
        float tmax = -INFINITY;
        #pragma unroll
        for (int f = 0; f < 4; ++f) {
            #pragma unroll
            for (int r = 0; r < 4; ++r) {
                const float s = sf[f][r] * SCALE2 + (1.0f - msk[f][r]) * NEG2;
                p[f][r] = s;
                tmax = fmaxf(tmax, s);
            }
        }
        tmax = fmaxf(tmax, __shfl_xor(tmax, 16));
        tmax = fmaxf(tmax, __shfl_xor(tmax, 32));
        const float mnew = fmaxf(mrun, tmax);
        const float fs = exp2f(mrun - mnew);
        float sum = 0.0f;
        #pragma unroll
        for (int f = 0; f < 4; ++f) {
            #pragma unroll
            for (int r = 0; r < 4; ++r) { p[f][r] = exp2f(p[f][r] - mnew); sum += p[f][r]; }
        }
        sum += __shfl_xor(sum, 16);
        sum += __shfl_xor(sum, 32);
        lrun = lrun * fs + sum;
        mrun = mnew;

        const float fr0 = __shfl(fs, hh * 4 + 0);
        const float fr1 = __shfl(fs, hh * 4 + 1);
        const float fr2 = __shfl(fs, hh * 4 + 2);
        const float fr3 = __shfl(fs, hh * 4 + 3);
        #pragma unroll
        for (int nf = 0; nf < 4; ++nf) {
            O[nf][0] *= fr0; O[nf][1] *= fr1; O[nf][2] *= fr2; O[nf][3] *= fr3;
        }

        unsigned pks[4][2];
        #pragma unroll
        for (int f = 0; f < 4; ++f) {
            pks[f][0] = pack_bf16(p[f][0], p[f][1]);
            pks[f][1] = pack_bf16(p[f][2], p[f][3]);
        }
        #pragma unroll
        for (int kh = 0; kh < 2; ++kh) {
            unsigned ad[4];
            #pragma unroll
            for (int wq = 0; wq < 4; ++wq) {
                const int pos = wq >> 1, ww = wq & 1;
                const int src = c + 16 * ((2 * hh + pos) & 3);
                const unsigned x = (unsigned)__shfl((int)pks[2 * kh][ww], src);
                const unsigned y = (unsigned)__shfl((int)pks[2 * kh + 1][ww], src);
                ad[wq] = (hh & 2) ? y : x;
            }
            const uint4 adv = make_uint4(ad[0], ad[1], ad[2], ad[3]);
            const bf16x8 pa = __builtin_bit_cast(bf16x8, adv);
            __builtin_amdgcn_s_setprio(1);
            #pragma unroll
            for (int nf = 0; nf < 4; ++nf) {
                O[nf] = __builtin_amdgcn_mfma_f32_16x16x32_bf16(
                            pa, __builtin_bit_cast(bf16x8, vf[cur][nf * 2 + kh][l]), O[nf], 0, 0, 0);
            }
            __builtin_amdgcn_s_setprio(0);
        }

        __syncthreads();
    }

    if (e < 0) {
        #pragma unroll
        for (int r = 0; r < 4; ++r) {
            const float lr  = __shfl(lrun, hh * 4 + r);
            const int   qg  = qb * 64 + w * 16 + hh * 4 + r;
            const float fmv = from_mask[b * M_ + qg];
            const float scl = fmv / lr;
            float* op = out + (((size_t)b * M_ + qg) * H_ + h) * 64 + c;
            #pragma unroll
            for (int nf = 0; nf < 4; ++nf) op[nf * 16] = O[nf][r] * scl;
        }
    } else {
        const int pe = (bh * 2 + e) * 8 + ch;
        #pragma unroll
        for (int r = 0; r < 4; ++r) {
            const int qlocal = w * 16 + hh * 4 + r;
            float* pa = ws + PACC_OFF + ((size_t)pe * 64 + qlocal) * 64 + c;
            #pragma unroll
            for (int nf = 0; nf < 4; ++nf) pa[nf * 16] = O[nf][r];
        }
        if (hh == 0) {
            ws[PM_OFF + pe * 64 + w * 16 + c] = mrun;
            ws[PL_OFF + pe * 64 + w * 16 + c] = lrun;
        }
    }
}

// Combine the 8 partials for each edge q-block row (m in log2 domain).
__global__ __launch_bounds__(256)
void bigbird_combine(const float* __restrict__ ws, const float* __restrict__ from_mask,
                     float* __restrict__ out)
{
    const int g  = blockIdx.x;          // bh*2 + e
    const int e  = g & 1;
    const int bh = g >> 1;
    const int h  = bh % H_;
    const int b  = bh / H_;
    const int qb = e ? NB_ - 1 : 0;

    const int t  = threadIdx.x;
    const int r  = t >> 2;
    const int dq = (t & 3) * 16;

    float mc[8], lc[8];
    float m = -INFINITY;
    #pragma unroll
    for (int c = 0; c < 8; ++c) {
        mc[c] = ws[PM_OFF + (g * 8 + c) * 64 + r];
        lc[c] = ws[PL_OFF + (g * 8 + c) * 64 + r];
        m = fmaxf(m, mc[c]);
    }
    float l = 0.0f;
    float acc[16];
    #pragma unroll
    for (int j = 0; j < 16; ++j) acc[j] = 0.0f;
    #pragma unroll
    for (int c = 0; c < 8; ++c) {
        const float sc = exp2f(mc[c] - m);
        l += lc[c] * sc;
        const float4* pa = (const float4*)(ws + PACC_OFF + ((size_t)(g * 8 + c) * 64 + r) * 64 + dq);
        #pragma unroll
        for (int j4 = 0; j4 < 4; ++j4) {
            float4 av = pa[j4];
            acc[j4 * 4 + 0] += sc * av.x;
            acc[j4 * 4 + 1] += sc * av.y;
            acc[j4 * 4 + 2] += sc * av.z;
            acc[j4 * 4 + 3] += sc * av.w;
        }
    }
    const float fm = from_mask[b * M_ + qb * 64 + r];
    const float s  = fm / l;
    float* op = out + (((size_t)b * M_ + qb * 64 + r) * H_ + h) * 64 + dq;
    #pragma unroll
    for (int j4 = 0; j4 < 4; ++j4) {
        float4 o;
        o.x = acc[j4 * 4 + 0] * s; o.y = acc[j4 * 4 + 1] * s;
        o.z = acc[j4 * 4 + 2] * s; o.w = acc[j4 * 4 + 3] * s;
        *(float4*)(op + j4 * 4) = o;
    }
}

extern "C" void kernel_launch(void* const* d_in, const int* in_sizes, int n_in,
                              void* d_out, int out_size, void* d_ws, size_t ws_size,
                              hipStream_t stream) {
    const float* q  = (const float*)d_in[0];
    const float* k  = (const float*)d_in[1];
    const float* v  = (const float*)d_in[2];
    const float* bm = (const float*)d_in[3];
    const float* fm = (const float*)d_in[4];
    const float* tm = (const float*)d_in[5];
    const float* fb = (const float*)d_in[6];
    const float* tb = (const float*)d_in[7];
    const int*   ra = (const int*)d_in[8];
    float* o  = (float*)d_out;
    float* ws = (float*)d_ws;

    if (ws_size >= WS_NEED) {
        int4* wskv = (int4*)((char*)d_ws + KV_BYTE_OFF);
        hipLaunchKernelGGL(bigbird_prep, dim3(B_ * H_ * 64), dim3(256), 0, stream,
                           k, v, wskv);
        hipLaunchKernelGGL(bigbird_1w, dim3(NWG1), dim3(64), 0, stream,
                           q, wskv, bm, fm, tm, fb, tb, ra, o, ws);
    } else {
        hipLaunchKernelGGL(bigbird_mfma, dim3(NWG), dim3(256), 0, stream,
                           q, k, v, bm, fm, tm, fb, tb, ra, o, ws);
    }
    hipLaunchKernelGGL(bigbird_combine, dim3(B_ * H_ * 2), dim3(256), 0, stream,
                       ws, fm, o);
}

// Round 16
// 94.564 us; speedup vs baseline: 1.1038x; 1.1038x over previous
//
#include <hip/hip_runtime.h>
#include <math.h>

// BigBird block-sparse attention.
// Path A: prep converts K,V -> bf16 fragment-linear tiles in d_ws; main kernel
//   = R8's 4-wave double-buffered-LDS structure, but staging via
//   __builtin_amdgcn_global_load_lds (16B width): no VGPR round-trip, no cvt,
//   half the staged bytes. One barrier per tile.
// Path B (fallback if ws too small): R10-style 4-wave kernel from fp32.
// B=2 H=16 M=N=4096 D=64 WM=WN=64 R=3 nb=64.
constexpr int B_  = 2;
constexpr int H_  = 16;
constexpr int M_  = 4096;
constexpr int NB_ = 64;
constexpr int R_  = 3;
constexpr float LOG2E  = 1.44269504089f;
constexpr float SCALE2 = 0.125f * LOG2E;          // (1/sqrt(64)) * log2(e)
constexpr float NEG2   = -10000.0f * LOG2E;

constexpr int PER_BH = 62 + 16;             // items per bh (62 mid + 2 edges*8)
constexpr int NWG    = B_ * H_ * PER_BH;    // 2496 = 8 * 312
constexpr int PACC_OFF = 0;                                  // [BH][2][8][64][64]
constexpr int PM_OFF   = B_ * H_ * 2 * 8 * 64 * 64;          // [BH][2][8][64]
constexpr int PL_OFF   = PM_OFF + B_ * H_ * 2 * 8 * 64;
constexpr size_t KV_BYTE_OFF = (size_t)(PL_OFF + B_ * H_ * 2 * 8 * 64) * 4;  // 8,650,752
constexpr size_t KV_BYTES    = (size_t)B_ * H_ * 64 * 1024 * 16;             // 33,554,432
constexpr size_t WS_NEED     = KV_BYTE_OFF + KV_BYTES;

typedef short bf16x8 __attribute__((ext_vector_type(8)));   // 8 bf16 in 4 VGPRs
typedef float f32x4  __attribute__((ext_vector_type(4)));

__device__ __forceinline__ short bf16s(float x) {
    return __builtin_bit_cast(short, (__bf16)x);
}
__device__ __forceinline__ unsigned pack_bf16(float a, float b) {
    unsigned short ul = __builtin_bit_cast(unsigned short, (__bf16)a);
    unsigned short uh = __builtin_bit_cast(unsigned short, (__bf16)b);
    return (unsigned)ul | ((unsigned)uh << 16);
}

// async global->LDS, 16B per lane: lane l's 16B from g+l lands at s + l*16.
__device__ __forceinline__ void gload_lds16(const int4* g, int4* s) {
    __builtin_amdgcn_global_load_lds(
        (const __attribute__((address_space(1))) void*)g,
        (__attribute__((address_space(3))) void*)s,
        16, 0, 0);
}

// key-block index for tile i (wave-uniform arithmetic, no arrays)
__device__ __forceinline__ int tile_kb(int e, int ch, int qb, int ra0, int ra1, int ra2, int i) {
    if (e >= 0) return ch * 8 + i;
    const int rnd = (i == 4) ? ra0 : ((i == 5) ? ra1 : ra2);
    if (qb == 1)        return (i < 3) ? i : ((i == 3) ? NB_ - 1 : rnd);
    if (qb == NB_ - 2)  return (i == 0) ? 0 : ((i < 4) ? 60 + i : rnd);
    if (i == 0) return 0;
    if (i < 4)  return qb - 2 + i;
    if (i < 7)  return rnd;
    return NB_ - 1;
}

// mask mode for tile i: 0=to_mask, 1=band, 2=rand
__device__ __forceinline__ int tile_mode(int e, int qb, int i, int& boff) {
    boff = 0;
    if (e >= 0) return 0;
    if (qb == 1 || qb == NB_ - 2) return (i >= 4) ? 2 : 0;
    if (i >= 1 && i < 4) { boff = (i - 1) * 64; return 1; }
    if (i >= 4 && i < 7) return 2;
    return 0;
}

// =====================================================================
// Prep: K,V fp32 -> bf16 fragment-linear tiles in ws.
// Tile (bh,kb) -> 1024 int4 chunks: chunk ch = slot*64 + lane.
//  slot 0..7  (K, s=f*2+dh): lane l holds K[16f+(l&15)][32dh+8*(l>>4)+j]
//  slot 8..15 (V, s=nf*2+kh): lane l holds V[32kh+8*(l>>4)+j][16nf+(l&15)]
// =====================================================================
__global__ __launch_bounds__(256)
void bigbird_prep(const float* __restrict__ k, const float* __restrict__ v,
                  int4* __restrict__ wskv)
{
    __shared__ float kt[64][66];
    __shared__ float vt[64][66];
    const int g = blockIdx.x;           // bh*64 + kb
    const int t = threadIdx.x;
    const int row = t >> 2, cc = (t & 3) * 16;
    const float* kp = k + (size_t)g * 4096 + row * 64 + cc;
    const float* vp = v + (size_t)g * 4096 + row * 64 + cc;
    #pragma unroll
    for (int j4 = 0; j4 < 4; ++j4) {
        *(float4*)&kt[row][cc + j4 * 4] = *(const float4*)(kp + j4 * 4);
        *(float4*)&vt[row][cc + j4 * 4] = *(const float4*)(vp + j4 * 4);
    }
    __syncthreads();
    #pragma unroll
    for (int cpt = 0; cpt < 4; ++cpt) {
        const int ch = t + cpt * 256;
        const int slot = ch >> 6, lane = ch & 63;
        bf16x8 o;
        if (slot < 8) {
            const int r  = 16 * (slot >> 1) + (lane & 15);
            const int c0 = 32 * (slot & 1) + 8 * (lane >> 4);
            #pragma unroll
            for (int j = 0; j < 8; ++j) o[j] = bf16s(kt[r][c0 + j]);
        } else {
            const int s2 = slot - 8;
            const int r0 = 32 * (s2 & 1) + 8 * (lane >> 4);
            const int c  = 16 * (s2 >> 1) + (lane & 15);
            #pragma unroll
            for (int j = 0; j < 8; ++j) o[j] = bf16s(vt[r0 + j][c]);
        }
        wskv[(size_t)g * 1024 + ch] = __builtin_bit_cast(int4, o);
    }
}

// =====================================================================
// Main (path A): 4 waves per block sharing LDS K/V (double-buffered),
// staged via global_load_lds from the bf16 fragment-linear cache.
// =====================================================================
__global__ __launch_bounds__(256, 4)
void bigbird_4w(const float* __restrict__ q, const int4* __restrict__ wskv,
                const float* __restrict__ band_mask, const float* __restrict__ from_mask,
                const float* __restrict__ to_mask,   const float* __restrict__ from_blocked,
                const float* __restrict__ to_blocked, const int* __restrict__ rand_attn,
                float* __restrict__ out, float* __restrict__ ws)
{
    __shared__ int4 tiles[2][16][64];   // 2 x 16KB = 32768 B exactly

    // bijective XCD swizzle: 2496 = 8 * 312 (4 bh per XCD chunk)
    const int wg  = (blockIdx.x & 7) * (NWG / 8) + (blockIdx.x >> 3);
    const int bh  = wg / PER_BH;
    const int idx = wg % PER_BH;
    const int h   = bh % H_;
    const int b   = bh / H_;
    int qb, e = -1, ch = 0;
    if (idx < 62)      { qb = idx + 1; }
    else if (idx < 70) { e = 0; ch = idx - 62; qb = 0; }
    else               { e = 1; ch = idx - 70; qb = NB_ - 1; }

    const int t  = threadIdx.x;
    const int l  = t & 63;
    const int w  = t >> 6;          // wave = q-strip
    const int c  = l & 15;
    const int hh = l >> 4;
    const int s0 = w * 4;           // this wave stages slots s0..s0+3

    int ra0 = 0, ra1 = 0, ra2 = 0;
    int nkb;
    if (e >= 0) nkb = 8;
    else {
        const int* ra = rand_attn + ((b * H_ + h) * (NB_ - 2) + (qb - 1)) * R_;
        ra0 = ra[0]; ra1 = ra[1]; ra2 = ra[2];
        nkb = (qb == 1 || qb == NB_ - 2) ? 7 : 8;
    }

    // Q B-fragments: lane holds Q[qb*64 + w*16 + c][32dh + hh*8 + j]
    bf16x8 qf[2];
    {
        const float* qp = q + ((size_t)bh * M_ + (size_t)qb * 64 + w * 16 + c) * 64 + hh * 8;
        #pragma unroll
        for (int dh = 0; dh < 2; ++dh) {
            float4 a0 = *(const float4*)(qp + dh * 32);
            float4 a1 = *(const float4*)(qp + dh * 32 + 4);
            bf16x8 qv;
            qv[0] = bf16s(a0.x); qv[1] = bf16s(a0.y); qv[2] = bf16s(a0.z); qv[3] = bf16s(a0.w);
            qv[4] = bf16s(a1.x); qv[5] = bf16s(a1.y); qv[6] = bf16s(a1.z); qv[7] = bf16s(a1.w);
            qf[dh] = qv;
        }
    }

    const float fbv = from_blocked[(b * NB_ + qb) * 64 + (w * 16 + c)];

    float mrun = -INFINITY, lrun = 0.0f;   // log2 domain
    f32x4 O[4];
    #pragma unroll
    for (int nf = 0; nf < 4; ++nf) { O[nf][0] = 0.f; O[nf][1] = 0.f; O[nf][2] = 0.f; O[nf][3] = 0.f; }

    // ---- prologue: stage tile 0 into buf 0 (async, drained by barrier)
    {
        const int kb0 = tile_kb(e, ch, qb, ra0, ra1, ra2, 0);
        const int4* tb = wskv + (size_t)(bh * 64 + kb0) * 1024;
        #pragma unroll
        for (int j = 0; j < 4; ++j)
            gload_lds16(tb + (s0 + j) * 64 + l, &tiles[0][s0 + j][0]);
    }
    __syncthreads();

    for (int it = 0; it < nkb; ++it) {
        const int cur = it & 1;
        const int kb = tile_kb(e, ch, qb, ra0, ra1, ra2, it);
        int boffC; const int modeC = tile_mode(e, qb, it, boffC);

        // ---- S^T = K * Q^T : lane holds S[q=c][k=16f+4hh+r]
        f32x4 sf[4];
        #pragma unroll
        for (int f = 0; f < 4; ++f) { sf[f][0]=0.f; sf[f][1]=0.f; sf[f][2]=0.f; sf[f][3]=0.f; }
        __builtin_amdgcn_s_setprio(1);
        #pragma unroll
        for (int f = 0; f < 4; ++f) {
            sf[f] = __builtin_amdgcn_mfma_f32_16x16x32_bf16(
                        __builtin_bit_cast(bf16x8, tiles[cur][f * 2 + 0][l]), qf[0], sf[f], 0, 0, 0);
            sf[f] = __builtin_amdgcn_mfma_f32_16x16x32_bf16(
                        __builtin_bit_cast(bf16x8, tiles[cur][f * 2 + 1][l]), qf[1], sf[f], 0, 0, 0);
        }
        __builtin_amdgcn_s_setprio(0);

        // ---- masks for CURRENT tile (vmem issued BEFORE the gl_lds prefetch,
        //      so softmax's mask-wait is vmcnt(4), not a full drain)
        float msk[4][4];
        if (modeC == 0) {
            const float* mp = to_mask + b * M_ + kb * 64 + 4 * hh;
            #pragma unroll
            for (int f = 0; f < 4; ++f) {
                float4 mv = *(const float4*)(mp + 16 * f);
                msk[f][0] = mv.x; msk[f][1] = mv.y; msk[f][2] = mv.z; msk[f][3] = mv.w;
            }
        } else if (modeC == 1) {
            const float* mp = band_mask + (((size_t)b * (NB_ - 4) + (qb - 2)) * 64 + (w * 16 + c)) * 192 + boffC + 4 * hh;
            #pragma unroll
            for (int f = 0; f < 4; ++f) {
                float4 mv = *(const float4*)(mp + 16 * f);
                msk[f][0] = mv.x; msk[f][1] = mv.y; msk[f][2] = mv.z; msk[f][3] = mv.w;
            }
        } else {
            const float* mp = to_blocked + (b * NB_ + kb) * 64 + 4 * hh;
            #pragma unroll
            for (int f = 0; f < 4; ++f) {
                float4 mv = *(const float4*)(mp + 16 * f);
                msk[f][0] = fbv * mv.x; msk[f][1] = fbv * mv.y;
                msk[f][2] = fbv * mv.z; msk[f][3] = fbv * mv.w;
            }
        }

        // ---- async stage tile it+1 into buf[nxt] (drained by the barrier,
        //      latency covered by softmax + PV)
        if (it + 1 < nkb) {
            const int kbn = tile_kb(e, ch, qb, ra0, ra1, ra2, it + 1);
            const int4* tb = wskv + (size_t)(bh * 64 + kbn) * 1024;
            const int nxt = cur ^ 1;
            #pragma unroll
            for (int j = 0; j < 4; ++j)
                gload_lds16(tb + (s0 + j) * 64 + l, &tiles[nxt][s0 + j][0]);
        }

        // ---- scale + mask + online softmax, log2 domain
        float p[4][4];
        float tmax = -INFINITY;
        #pragma unroll
        for (int f = 0; f < 4; ++f) {
            #pragma unroll
            for (int r = 0; r < 4; ++r) {
                const float s = sf[f][r] * SCALE2 + (1.0f - msk[f][r]) * NEG2;
                p[f][r] = s;
                tmax = fmaxf(tmax, s);
            }
        }
        tmax = fmaxf(tmax, __shfl_xor(tmax, 16));
        tmax = fmaxf(tmax, __shfl_xor(tmax, 32));
        const float mnew = fmaxf(mrun, tmax);
        const float fs = exp2f(mrun - mnew);
        float sum = 0.0f;
        #pragma unroll
        for (int f = 0; f < 4; ++f) {
            #pragma unroll
            for (int r = 0; r < 4; ++r) { p[f][r] = exp2f(p[f][r] - mnew); sum += p[f][r]; }
        }
        sum += __shfl_xor(sum, 16);
        sum += __shfl_xor(sum, 32);
        lrun = lrun * fs + sum;
        mrun = mnew;

        // ---- rescale O
        const float fr0 = __shfl(fs, hh * 4 + 0);
        const float fr1 = __shfl(fs, hh * 4 + 1);
        const float fr2 = __shfl(fs, hh * 4 + 2);
        const float fr3 = __shfl(fs, hh * 4 + 3);
        #pragma unroll
        for (int nf = 0; nf < 4; ++nf) {
            O[nf][0] *= fr0; O[nf][1] *= fr1; O[nf][2] *= fr2; O[nf][3] *= fr3;
        }

        // ---- P -> bf16, redistribute to PV A-frag layout, PV
        unsigned pks[4][2];
        #pragma unroll
        for (int f = 0; f < 4; ++f) {
            pks[f][0] = pack_bf16(p[f][0], p[f][1]);
            pks[f][1] = pack_bf16(p[f][2], p[f][3]);
        }
        #pragma unroll
        for (int kh = 0; kh < 2; ++kh) {
            unsigned ad[4];
            #pragma unroll
            for (int wq = 0; wq < 4; ++wq) {
                const int pos = wq >> 1, ww = wq & 1;
                const int src = c + 16 * ((2 * hh + pos) & 3);
                const unsigned x = (unsigned)__shfl((int)pks[2 * kh][ww], src);
                const unsigned y = (unsigned)__shfl((int)pks[2 * kh + 1][ww], src);
                ad[wq] = (hh & 2) ? y : x;
            }
            const uint4 adv = make_uint4(ad[0], ad[1], ad[2], ad[3]);
            const bf16x8 pa = __builtin_bit_cast(bf16x8, adv);
            __builtin_amdgcn_s_setprio(1);
            #pragma unroll
            for (int nf = 0; nf < 4; ++nf) {
                O[nf] = __builtin_amdgcn_mfma_f32_16x16x32_bf16(
                            pa, __builtin_bit_cast(bf16x8, tiles[cur][8 + nf * 2 + kh][l]), O[nf], 0, 0, 0);
            }
            __builtin_amdgcn_s_setprio(0);
        }

        __syncthreads();   // drains gl_lds (covered) + LDS-consume fence
    }

    // ---- epilogue: O rows q_local = w*16 + 4hh + r, cols d = nf*16 + c
    if (e < 0) {
        #pragma unroll
        for (int r = 0; r < 4; ++r) {
            const float lr  = __shfl(lrun, hh * 4 + r);
            const int   qg  = qb * 64 + w * 16 + hh * 4 + r;
            const float fmv = from_mask[b * M_ + qg];
            const float scl = fmv / lr;
            float* op = out + (((size_t)b * M_ + qg) * H_ + h) * 64 + c;
            #pragma unroll
            for (int nf = 0; nf < 4; ++nf) op[nf * 16] = O[nf][r] * scl;
        }
    } else {
        const int pe = (bh * 2 + e) * 8 + ch;
        #pragma unroll
        for (int r = 0; r < 4; ++r) {
            const int qlocal = w * 16 + hh * 4 + r;
            float* pa = ws + PACC_OFF + ((size_t)pe * 64 + qlocal) * 64 + c;
            #pragma unroll
            for (int nf = 0; nf < 4; ++nf) pa[nf * 16] = O[nf][r];
        }
        if (hh == 0) {
            ws[PM_OFF + pe * 64 + w * 16 + c] = mrun;   // log2 domain
            ws[PL_OFF + pe * 64 + w * 16 + c] = lrun;
        }
    }
}

// =====================================================================
// Fallback (path B): 4-wave LDS double-buffered from fp32 (R10 kernel).
// =====================================================================
__global__ __launch_bounds__(256, 4)
void bigbird_mfma(const float* __restrict__ q,  const float* __restrict__ k,
                  const float* __restrict__ v,  const float* __restrict__ band_mask,
                  const float* __restrict__ from_mask, const float* __restrict__ to_mask,
                  const float* __restrict__ from_blocked, const float* __restrict__ to_blocked,
                  const int*   __restrict__ rand_attn,   float* __restrict__ out,
                  float* __restrict__ ws)
{
    __shared__ int4 kf[2][8][64];
    __shared__ int4 vf[2][8][64];

    const int wg  = (blockIdx.x & 7) * (NWG / 8) + (blockIdx.x >> 3);
    const int bh  = wg / PER_BH;
    const int idx = wg % PER_BH;
    const int h   = bh % H_;
    const int b   = bh / H_;
    int qb, e = -1, ch = 0;
    if (idx < 62)      { qb = idx + 1; }
    else if (idx < 70) { e = 0; ch = idx - 62; qb = 0; }
    else               { e = 1; ch = idx - 70; qb = NB_ - 1; }

    const int t  = threadIdx.x;
    const int l  = t & 63;
    const int w  = t >> 6;
    const int c  = l & 15;
    const int hh = l >> 4;

    int ra0 = 0, ra1 = 0, ra2 = 0;
    int nkb;
    if (e >= 0) nkb = 8;
    else {
        const int* ra = rand_attn + ((b * H_ + h) * (NB_ - 2) + (qb - 1)) * R_;
        ra0 = ra[0]; ra1 = ra[1]; ra2 = ra[2];
        nkb = (qb == 1 || qb == NB_ - 2) ? 7 : 8;
    }

    const int rr  = t >> 2;
    const int cc4 = t & 3;
    const float* kbase = k + ((size_t)bh * M_ + rr) * 64 + cc4 * 16;
    const int kslot = (rr >> 4) * 2 + (cc4 >> 1);
    const int kr15  = rr & 15;
    const int kg0   = (cc4 & 1) * 2;

    const int d0v  = (t & 31) * 2;
    const int oct8 = t >> 5;
    const float* vbase = v + (size_t)bh * M_ * 64 + (size_t)(oct8 * 8) * 64 + d0v;
    const int vslot = (d0v >> 4) * 2 + (oct8 >> 2);
    const int vidx  = (oct8 & 3) * 16 + (d0v & 15);

    bf16x8 qf[2];
    {
        const float* qp = q + ((size_t)bh * M_ + (size_t)qb * 64 + w * 16 + c) * 64 + hh * 8;
        #pragma unroll
        for (int dh = 0; dh < 2; ++dh) {
            float4 a0 = *(const float4*)(qp + dh * 32);
            float4 a1 = *(const float4*)(qp + dh * 32 + 4);
            bf16x8 qv;
            qv[0] = bf16s(a0.x); qv[1] = bf16s(a0.y); qv[2] = bf16s(a0.z); qv[3] = bf16s(a0.w);
            qv[4] = bf16s(a1.x); qv[5] = bf16s(a1.y); qv[6] = bf16s(a1.z); qv[7] = bf16s(a1.w);
            qf[dh] = qv;
        }
    }

    const float fbv = from_blocked[(b * NB_ + qb) * 64 + (w * 16 + c)];

    float mrun = -INFINITY, lrun = 0.0f;
    f32x4 O[4];
    #pragma unroll
    for (int nf = 0; nf < 4; ++nf) { O[nf][0] = 0.f; O[nf][1] = 0.f; O[nf][2] = 0.f; O[nf][3] = 0.f; }

    float4 kr0, kr1, kr2, kr3;
    float2 vr[8];

    {
        const int kb0 = tile_kb(e, ch, qb, ra0, ra1, ra2, 0);
        const float4* kp4 = (const float4*)(kbase + (size_t)kb0 * 4096);
        kr0 = kp4[0]; kr1 = kp4[1]; kr2 = kp4[2]; kr3 = kp4[3];
        const float* vp = vbase + (size_t)kb0 * 4096;
        #pragma unroll
        for (int j = 0; j < 8; ++j) vr[j] = *(const float2*)(vp + j * 64);

        float kfl[16];
        kfl[0]=kr0.x; kfl[1]=kr0.y; kfl[2]=kr0.z; kfl[3]=kr0.w;
        kfl[4]=kr1.x; kfl[5]=kr1.y; kfl[6]=kr1.z; kfl[7]=kr1.w;
        kfl[8]=kr2.x; kfl[9]=kr2.y; kfl[10]=kr2.z; kfl[11]=kr2.w;
        kfl[12]=kr3.x; kfl[13]=kr3.y; kfl[14]=kr3.z; kfl[15]=kr3.w;
        bf16x8 o0, o1;
        #pragma unroll
        for (int j = 0; j < 8; ++j) { o0[j] = bf16s(kfl[j]); o1[j] = bf16s(kfl[8 + j]); }
        kf[0][kslot][kg0 * 16 + kr15]       = __builtin_bit_cast(int4, o0);
        kf[0][kslot][(kg0 + 1) * 16 + kr15] = __builtin_bit_cast(int4, o1);

        bf16x8 va, vb2;
        #pragma unroll
        for (int j = 0; j < 8; ++j) { va[j] = bf16s(vr[j].x); vb2[j] = bf16s(vr[j].y); }
        vf[0][vslot][vidx]     = __builtin_bit_cast(int4, va);
        vf[0][vslot][vidx + 1] = __builtin_bit_cast(int4, vb2);

        if (1 < nkb) {
            const int kb1 = tile_kb(e, ch, qb, ra0, ra1, ra2, 1);
            const float4* kn4 = (const float4*)(kbase + (size_t)kb1 * 4096);
            kr0 = kn4[0]; kr1 = kn4[1]; kr2 = kn4[2]; kr3 = kn4[3];
            const float* vn = vbase + (size_t)kb1 * 4096;
            #pragma unroll
            for (int j = 0; j < 8; ++j) vr[j] = *(const float2*)(vn + j * 64);
        }
    }
    __syncthreads();

    for (int it = 0; it < nkb; ++it) {
        const int cur = it & 1;
        const int kb = tile_kb(e, ch, qb, ra0, ra1, ra2, it);
        int boffC; const int modeC = tile_mode(e, qb, it, boffC);

        f32x4 sf[4];
        #pragma unroll
        for (int f = 0; f < 4; ++f) { sf[f][0]=0.f; sf[f][1]=0.f; sf[f][2]=0.f; sf[f][3]=0.f; }
        __builtin_amdgcn_s_setprio(1);
        #pragma unroll
        for (int f = 0; f < 4; ++f) {
            sf[f] = __builtin_amdgcn_mfma_f32_16x16x32_bf16(
                        __builtin_bit_cast(bf16x8, kf[cur][f * 2 + 0][l]), qf[0], sf[f], 0, 0, 0);
            sf[f] = __builtin_amdgcn_mfma_f32_16x16x32_bf16(
                        __builtin_bit_cast(bf16x8, kf[cur][f * 2 + 1][l]), qf[1], sf[f], 0, 0, 0);
        }
        __builtin_amdgcn_s_setprio(0);

        if (it + 1 < nkb) {
            const int nxt = cur ^ 1;
            float kfl[16];
            kfl[0]=kr0.x; kfl[1]=kr0.y; kfl[2]=kr0.z; kfl[3]=kr0.w;
            kfl[4]=kr1.x; kfl[5]=kr1.y; kfl[6]=kr1.z; kfl[7]=kr1.w;
            kfl[8]=kr2.x; kfl[9]=kr2.y; kfl[10]=kr2.z; kfl[11]=kr2.w;
            kfl[12]=kr3.x; kfl[13]=kr3.y; kfl[14]=kr3.z; kfl[15]=kr3.w;
            bf16x8 o0, o1;
            #pragma unroll
            for (int j = 0; j < 8; ++j) { o0[j] = bf16s(kfl[j]); o1[j] = bf16s(kfl[8 + j]); }
            kf[nxt][kslot][kg0 * 16 + kr15]       = __builtin_bit_cast(int4, o0);
            kf[nxt][kslot][(kg0 + 1) * 16 + kr15] = __builtin_bit_cast(int4, o1);

            bf16x8 va, vb2;
            #pragma unroll
            for (int j = 0; j < 8; ++j) { va[j] = bf16s(vr[j].x); vb2[j] = bf16s(vr[j].y); }
            vf[nxt][vslot][vidx]     = __builtin_bit_cast(int4, va);
            vf[nxt][vslot][vidx + 1] = __builtin_bit_cast(int4, vb2);
        }

        float msk[4][4];
        if (modeC == 0) {
            const float* mp = to_mask + b * M_ + kb * 64 + 4 * hh;
            #pragma unroll
            for (int f = 0; f < 4; ++f) {
                float4 mv = *(const float4*)(mp + 16 * f);
                msk[f][0] = mv.x; msk[f][1] = mv.y; msk[f][2] = mv.z; msk[f][3] = mv.w;
            }
        } else if (modeC == 1) {
            const float* mp = band_mask + (((size_t)b * (NB_ - 4) + (qb - 2)) * 64 + (w * 16 + c)) * 192 + boffC + 4 * hh;
            #pragma unroll
            for (int f = 0; f < 4; ++f) {
                float4 mv = *(const float4*)(mp + 16 * f);
                msk[f][0] = mv.x; msk[f][1] = mv.y; msk[f][2] = mv.z; msk[f][3] = mv.w;
            }
        } else {
            const float* mp = to_blocked + (b * NB_ + kb) * 64 + 4 * hh;
            #pragma unroll
            for (int f = 0; f < 4; ++f) {
                float4 mv = *(const float4*)(mp + 16 * f);
                msk[f][0] = fbv * mv.x; msk[f][1] = fbv * mv.y;
                msk[f][2] = fbv * mv.z; msk[f][3] = fbv * mv.w;
            }
        }

        if (it + 2 < nkb) {
            const int kb2 = tile_kb(e, ch, qb, ra0, ra1, ra2, it + 2);
            const float4* kp4 = (const float4*)(kbase + (size_t)kb2 * 4096);
            kr0 = kp4[0]; kr1 = kp4[1]; kr2 = kp4[2]; kr3 = kp4[3];
            const float* vp = vbase + (size_t)kb2 * 4096;
            #pragma unroll
            for (int j = 0; j < 8; ++j) vr[j] = *(const float2*)(vp + j * 64);
        }

        float p[4][4];
        float tmax = -INFINITY;
        #pragma unroll
        for (int f = 0; f < 4; ++f) {
            #pragma unroll
            for (int r = 0; r < 4; ++r) {
                const float s = sf[f][r] * SCALE2 + (1.0f - msk[f][r]) * NEG2;
                p[f][r] = s;
                tmax = fmaxf(tmax, s);
            }
        }
        tmax = fmaxf(tmax, __shfl_xor(tmax, 16));
        tmax = fmaxf(tmax, __shfl_xor(tmax, 32));
        const float mnew = fmaxf(mrun, tmax);
        const float fs = exp2f(mrun - mnew);
        float sum = 0.0f;
        #pragma unroll
        for (int f = 0; f < 4; ++f) {
            #pragma unroll
            for (int r = 0; r < 4; ++r) { p[f][r] = exp2f(p[f][r] - mnew); sum += p[f][r]; }
        }
        sum += __shfl_xor(sum, 16);
        sum += __shfl_xor(sum, 32);
        lrun = lrun * fs + sum;
        mrun = mnew;

        const float fr0 = __shfl(fs, hh * 4 + 0);
        const float fr1 = __shfl(fs, hh * 4 + 1);
        const float fr2 = __shfl(fs, hh * 4 + 2);
        const float fr3 = __shfl(fs, hh * 4 + 3);
        #pragma unroll
        for (int nf = 0; nf < 4; ++nf) {
            O[nf][0] *= fr0; O[nf][1] *= fr1; O[nf][2] *= fr2; O[nf][3] *= fr3;
        }

        unsigned pks[4][2];
        #pragma unroll
        for (int f = 0; f < 4; ++f) {
            pks[f][0] = pack_bf16(p[f][0], p[f][1]);
            pks[f][1] = pack_bf16(p[f][2], p[f][3]);
        }
        #pragma unroll
        for (int kh = 0; kh < 2; ++kh) {
            unsigned ad[4];
            #pragma unroll
            for (int wq = 0; wq < 4; ++wq) {
                const int pos = wq >> 1, ww = wq & 1;
                const int src = c + 16 * ((2 * hh + pos) & 3);
                const unsigned x = (unsigned)__shfl((int)pks[2 * kh][ww], src);
                const unsigned y = (unsigned)__shfl((int)pks[2 * kh + 1][ww], src);
                ad[wq] = (hh & 2) ? y : x;
            }
            const uint4 adv = make_uint4(ad[0], ad[1], ad[2], ad[3]);
            const bf16x8 pa = __builtin_bit_cast(bf16x8, adv);
            __builtin_amdgcn_s_setprio(1);
            #pragma unroll
            for (int nf = 0; nf < 4; ++nf) {
                O[nf] = __builtin_amdgcn_mfma_f32_16x16x32_bf16(
                            pa, __builtin_bit_cast(bf16x8, vf[cur][nf * 2 + kh][l]), O[nf], 0, 0, 0);
            }
            __builtin_amdgcn_s_setprio(0);
        }

        __syncthreads();
    }

    if (e < 0) {
        #pragma unroll
        for (int r = 0; r < 4; ++r) {
            const float lr  = __shfl(lrun, hh * 4 + r);
            const int   qg  = qb * 64 + w * 16 + hh * 4 + r;
            const float fmv = from_mask[b * M_ + qg];
            const float scl = fmv / lr;
            float* op = out + (((size_t)b * M_ + qg) * H_ + h) * 64 + c;
            #pragma unroll
            for (int nf = 0; nf < 4; ++nf) op[nf * 16] = O[nf][r] * scl;
        }
    } else {
        const int pe = (bh * 2 + e) * 8 + ch;
        #pragma unroll
        for (int r = 0; r < 4; ++r) {
            const int qlocal = w * 16 + hh * 4 + r;
            float* pa = ws + PACC_OFF + ((size_t)pe * 64 + qlocal) * 64 + c;
            #pragma unroll
            for (int nf = 0; nf < 4; ++nf) pa[nf * 16] = O[nf][r];
        }
        if (hh == 0) {
            ws[PM_OFF + pe * 64 + w * 16 + c] = mrun;
            ws[PL_OFF + pe * 64 + w * 16 + c] = lrun;
        }
    }
}

// Combine the 8 partials for each edge q-block row (m in log2 domain).
__global__ __launch_bounds__(256)
void bigbird_combine(const float* __restrict__ ws, const float* __restrict__ from_mask,
                     float* __restrict__ out)
{
    const int g  = blockIdx.x;          // bh*2 + e
    const int e  = g & 1;
    const int bh = g >> 1;
    const int h  = bh % H_;
    const int b  = bh / H_;
    const int qb = e ? NB_ - 1 : 0;

    const int t  = threadIdx.x;
    const int r  = t >> 2;
    const int dq = (t & 3) * 16;

    float mc[8], lc[8];
    float m = -INFINITY;
    #pragma unroll
    for (int c = 0; c < 8; ++c) {
        mc[c] = ws[PM_OFF + (g * 8 + c) * 64 + r];
        lc[c] = ws[PL_OFF + (g * 8 + c) * 64 + r];
        m = fmaxf(m, mc[c]);
    }
    float l = 0.0f;
    float acc[16];
    #pragma unroll
    for (int j = 0; j < 16; ++j) acc[j] = 0.0f;
    #pragma unroll
    for (int c = 0; c < 8; ++c) {
        const float sc = exp2f(mc[c] - m);
        l += lc[c] * sc;
        const float4* pa = (const float4*)(ws + PACC_OFF + ((size_t)(g * 8 + c) * 64 + r) * 64 + dq);
        #pragma unroll
        for (int j4 = 0; j4 < 4; ++j4) {
            float4 av = pa[j4];
            acc[j4 * 4 + 0] += sc * av.x;
            acc[j4 * 4 + 1] += sc * av.y;
            acc[j4 * 4 + 2] += sc * av.z;
            acc[j4 * 4 + 3] += sc * av.w;
        }
    }
    const float fm = from_mask[b * M_ + qb * 64 + r];
    const float s  = fm / l;
    float* op = out + (((size_t)b * M_ + qb * 64 + r) * H_ + h) * 64 + dq;
    #pragma unroll
    for (int j4 = 0; j4 < 4; ++j4) {
        float4 o;
        o.x = acc[j4 * 4 + 0] * s; o.y = acc[j4 * 4 + 1] * s;
        o.z = acc[j4 * 4 + 2] * s; o.w = acc[j4 * 4 + 3] * s;
        *(float4*)(op + j4 * 4) = o;
    }
}

extern "C" void kernel_launch(void* const* d_in, const int* in_sizes, int n_in,
                              void* d_out, int out_size, void* d_ws, size_t ws_size,
                              hipStream_t stream) {
    const float* q  = (const float*)d_in[0];
    const float* k  = (const float*)d_in[1];
    const float* v  = (const float*)d_in[2];
    const float* bm = (const float*)d_in[3];
    const float* fm = (const float*)d_in[4];
    const float* tm = (const float*)d_in[5];
    const float* fb = (const float*)d_in[6];
    const float* tb = (const float*)d_in[7];
    const int*   ra = (const int*)d_in[8];
    float* o  = (float*)d_out;
    float* ws = (float*)d_ws;

    if (ws_size >= WS_NEED) {
        int4* wskv = (int4*)((char*)d_ws + KV_BYTE_OFF);
        hipLaunchKernelGGL(bigbird_prep, dim3(B_ * H_ * 64), dim3(256), 0, stream,
                           k, v, wskv);
        hipLaunchKernelGGL(bigbird_4w, dim3(NWG), dim3(256), 0, stream,
                           q, wskv, bm, fm, tm, fb, tb, ra, o, ws);
    } else {
        hipLaunchKernelGGL(bigbird_mfma, dim3(NWG), dim3(256), 0, stream,
                           q, k, v, bm, fm, tm, fb, tb, ra, o, ws);
    }
    hipLaunchKernelGGL(bigbird_combine, dim3(B_ * H_ * 2), dim3(256), 0, stream,
                       ws, fm, o);
}